// Round 5
// baseline (3072.995 us; speedup 1.0000x reference)
//
#include <hip/hip_runtime.h>
#include <hip/hip_fp16.h>
#include <cstdint>
#include <cstddef>

typedef _Float16 f16;
typedef _Float16 half8 __attribute__((ext_vector_type(8)));
typedef _Float16 half4 __attribute__((ext_vector_type(4)));
typedef float floatx4 __attribute__((ext_vector_type(4)));

static constexpr size_t NB  = 16384;
static constexpr size_t DH  = 2048;
static constexpr size_t F1  = 1024;
static constexpr size_t F2  = 512;
static constexpr size_t CD  = 256;
static constexpr size_t KCB = 512;

// ---- d_out element offsets (all float32) ----
static constexpr size_t ZE_OFF  = 0;
static constexpr size_t ZQ_OFF  = NB * CD;
static constexpr size_t HR_OFF  = 2 * NB * CD;
static constexpr size_t IDX_OFF = 2 * NB * CD + NB * DH;

// ---- workspace byte offsets ----
static constexpr size_t O_HH   = 0;                   // h hi [NB,DH] f16
static constexpr size_t O_HL   = O_HH + NB * DH * 2;  // h lo
static constexpr size_t R1_END = O_HL + NB * DH * 2;

static constexpr size_t R_X1H = 0;                    // [NB,F1] f16
static constexpr size_t R_X1L = NB * F1 * 2;
static constexpr size_t R_X2F = 2 * NB * F1 * 2;      // [NB,F2] f32
static constexpr size_t R_X2H = R_X2F + NB * F2 * 4;
static constexpr size_t R_X2L = R_X2H + NB * F2 * 2;
static constexpr size_t R_Y1F = 0;                    // [NB,F2] f32
static constexpr size_t R_Y1H = NB * F2 * 4;          // [NB,F2] f16
static constexpr size_t R_Y2H = 0;                    // [NB,F1] f16

static constexpr size_t O_W1H = R1_END;
static constexpr size_t O_W1L = O_W1H + F1 * DH * 2;
static constexpr size_t O_W2H = O_W1L + F1 * DH * 2;
static constexpr size_t O_W2L = O_W2H + F2 * F1 * 2;
static constexpr size_t O_W3H = O_W2L + F2 * F1 * 2;
static constexpr size_t O_W3L = O_W3H + CD * F2 * 2;
static constexpr size_t O_CBH = O_W3L + CD * F2 * 2;
static constexpr size_t O_CBL = O_CBH + KCB * CD * 2;
static constexpr size_t O_DW1 = O_CBL + KCB * CD * 2;
static constexpr size_t O_DW2 = O_DW1 + F2 * CD * 2;
static constexpr size_t O_DW3 = O_DW2 + F1 * F2 * 2;
static constexpr size_t O_SUM = O_DW3 + DH * F1 * 2;  // 4 layers x 1024 doubles
static constexpr size_t O_SQ  = O_SUM + 4 * 1024 * 8;
static constexpr size_t O_SC  = O_SQ + 4 * 1024 * 8;
static constexpr size_t O_SH  = O_SC + 4 * 1024 * 4;
static constexpr size_t O_CN  = O_SH + 4 * 1024 * 4;
static constexpr size_t R2    = (O_CN + 4096 + 255) & ~(size_t)255;
static constexpr size_t R2_X1F = R2;                  // [NB,F1] f32
static constexpr size_t R2_ZEH = R2;                  // [NB,CD] f16
static constexpr size_t R2_ZEL = R2 + NB * CD * 2;
static constexpr size_t R2_S   = R2 + 2 * NB * CD * 2;   // [NB,KCB] f32
static constexpr size_t R2_ZQH = R2_S + NB * KCB * 4;    // [NB,CD] f16
static constexpr size_t R2_Y2F = R2;                  // [NB,F1] f32

#define GLLDS(src, dst)                                                          \
    __builtin_amdgcn_global_load_lds(                                            \
        (const __attribute__((address_space(1))) void*)(src),                    \
        (__attribute__((address_space(3))) void*)(dst), 16, 0, 0)

#define VMCNT(n)  asm volatile("s_waitcnt vmcnt(" #n ")" ::: "memory")
#define LGKMCNT0  asm volatile("s_waitcnt lgkmcnt(0)" ::: "memory")

// ============================================================================
// gemm3_v3: C[M,N](f32) = Ah*Bh^T + Ah*Bl^T + Al*Bh^T (f16 hi/lo, f32 accum)
// 1024 threads, 16 waves (4M x 4N), tile 256x256, BK=32, wave tile 64x64.
// A(hi+lo) staged to LDS (merged [256][64], XOR swizzle s^(r&7), 64KB dbuf);
// B fragments loaded direct global->VGPR (L1/L2-resident panel), 1 tile ahead.
// One barrier/K-tile; counted vmcnt: pre-MFMA vmcnt(10), pre-barrier vmcnt(8).
// XCD swizzle: y-major panels per XCD.
// ============================================================================
template<bool BIAS, bool STATS>
__global__ __launch_bounds__(1024)
void gemm3_v3(const f16* __restrict__ Ah_, const f16* __restrict__ Al_,
              const f16* __restrict__ Bh_, const f16* __restrict__ Bl_,
              float* __restrict__ C, const float* __restrict__ bias,
              double* __restrict__ ssum, double* __restrict__ ssq,
              int M, int N, int K)
{
    __shared__ f16 sA[2][16384];
    const int tid = threadIdx.x, lane = tid & 63, w = tid >> 6;
    const int wr = w >> 2, wn = w & 3;
    const int gx = gridDim.x;
    int id = blockIdx.x + gx * blockIdx.y;
    const int nwg = gx * gridDim.y;
    id = (id & 7) * (nwg >> 3) + (id >> 3);
    const int row0 = (id % gx) * 256, col0 = (id / gx) * 256;
    const int KT = K >> 5;

    // A staging: 2 gload_lds/wave/tile, each covers 8 rows x 8 slots (1KB).
    const int p = (lane & 7) ^ ((lane >> 3) & 7);      // logical slot (pre-swz src)
    const int r0 = w * 16 + (lane >> 3);
    const f16* srcA0 = (p < 4) ? Ah_ + (size_t)(row0 + r0) * K + p * 8
                               : Al_ + (size_t)(row0 + r0) * K + (p - 4) * 8;
    const f16* srcA1 = srcA0 + (size_t)8 * K;
    const int dstoff0 = w * 16 * 64, dstoff1 = (w * 16 + 8) * 64;

    // B fragment addresses (global, [N,K])
    const int l15 = lane & 15, sl = lane >> 4;
    size_t offB[4];
#pragma unroll
    for (int n = 0; n < 4; ++n)
        offB[n] = (size_t)(col0 + wn * 64 + n * 16 + l15) * K + sl * 8;

    // A fragment LDS offsets: logical slot sl (H) / 4+sl (L) at phys q^(r&7)
    int rdAH[4], rdAL[4];
#pragma unroll
    for (int m = 0; m < 4; ++m) {
        const int rA = wr * 64 + m * 16 + l15;
        rdAH[m] = rA * 64 + ((sl ^ (rA & 7)) << 3);
        rdAL[m] = rA * 64 + (((4 + sl) ^ (rA & 7)) << 3);
    }

    floatx4 acc[4][4];
#pragma unroll
    for (int m = 0; m < 4; ++m)
#pragma unroll
        for (int n = 0; n < 4; ++n)
#pragma unroll
            for (int j = 0; j < 4; ++j) acc[m][n][j] = 0.f;

    half8 bh0[4], bl0[4], bh1[4], bl1[4];

    // ---- prologue: stage A(0); load B(0) into set 0 ----
    GLLDS(srcA0, &sA[0][dstoff0]);
    GLLDS(srcA1, &sA[0][dstoff1]);
#pragma unroll
    for (int n = 0; n < 4; ++n) {
        bh0[n] = *(const half8*)(Bh_ + offB[n]);
        bl0[n] = *(const half8*)(Bl_ + offB[n]);
    }
    VMCNT(8);            // A(0) landed (B(0) x8 in flight)
    __builtin_amdgcn_s_barrier();

#define G3_BODY(pcur, pnxt, bhc, blc, bhn, bln, kt_)                              \
  {                                                                               \
    const int kn_ = ((kt_) + 1 < KT ? (kt_) + 1 : (kt_)) << 5;                    \
    half8 afh[4], afl[4];                                                         \
    _Pragma("unroll") for (int m = 0; m < 4; ++m) {                               \
        afh[m] = *(const half8*)((pcur) + rdAH[m]);                               \
        afl[m] = *(const half8*)((pcur) + rdAL[m]);                               \
    }                                                                             \
    GLLDS(srcA0 + kn_, (pnxt) + dstoff0);                                         \
    GLLDS(srcA1 + kn_, (pnxt) + dstoff1);                                         \
    _Pragma("unroll") for (int n = 0; n < 4; ++n) {                               \
        bhn[n] = *(const half8*)(Bh_ + offB[n] + kn_);                            \
        bln[n] = *(const half8*)(Bl_ + offB[n] + kn_);                            \
    }                                                                             \
    VMCNT(10); LGKMCNT0;                                                          \
    __builtin_amdgcn_sched_barrier(0);                                            \
    __builtin_amdgcn_s_setprio(1);                                                \
    _Pragma("unroll") for (int m = 0; m < 4; ++m)                                 \
      _Pragma("unroll") for (int n = 0; n < 4; ++n)                               \
        acc[m][n] = __builtin_amdgcn_mfma_f32_16x16x32_f16(afh[m], bhc[n], acc[m][n], 0, 0, 0); \
    _Pragma("unroll") for (int m = 0; m < 4; ++m)                                 \
      _Pragma("unroll") for (int n = 0; n < 4; ++n)                               \
        acc[m][n] = __builtin_amdgcn_mfma_f32_16x16x32_f16(afh[m], blc[n], acc[m][n], 0, 0, 0); \
    _Pragma("unroll") for (int m = 0; m < 4; ++m)                                 \
      _Pragma("unroll") for (int n = 0; n < 4; ++n)                               \
        acc[m][n] = __builtin_amdgcn_mfma_f32_16x16x32_f16(afl[m], bhc[n], acc[m][n], 0, 0, 0); \
    __builtin_amdgcn_s_setprio(0);                                                \
    VMCNT(8);                                                                     \
    __builtin_amdgcn_s_barrier();                                                 \
  }

    f16* b0 = &sA[0][0];
    f16* b1 = &sA[1][0];
    for (int kt = 0; kt < KT; kt += 2) {
        G3_BODY(b0, b1, bh0, bl0, bh1, bl1, kt);
        G3_BODY(b1, b0, bh1, bl1, bh0, bl0, kt + 1);
    }
    VMCNT(0);
#undef G3_BODY

    // ---- epilogue: C/D layout col = lane&15, row = (lane>>4)*4 + j ----
    const int cb0 = col0 + wn * 64;
    const int rb0 = row0 + wr * 64 + (lane >> 4) * 4;
#pragma unroll
    for (int n = 0; n < 4; ++n) {
        const int col = cb0 + n * 16 + l15;
        const float bv = BIAS ? bias[col] : 0.f;
        double sd = 0.0, sq = 0.0;
#pragma unroll
        for (int m = 0; m < 4; ++m) {
            const int row = rb0 + m * 16;
#pragma unroll
            for (int j = 0; j < 4; ++j) {
                const float v = acc[m][n][j] + bv;
                C[(size_t)(row + j) * N + col] = v;
                if (STATS) { sd += (double)v; sq += (double)v * (double)v; }
            }
        }
        if (STATS) {
            sd += __shfl_xor(sd, 16); sd += __shfl_xor(sd, 32);
            sq += __shfl_xor(sq, 16); sq += __shfl_xor(sq, 32);
            if (lane < 16) { atomicAdd(ssum + col, sd); atomicAdd(ssq + col, sq); }
        }
    }
}

// ============================================================================
// gemm1_v3 (decoder): C = A*B^T, f16 A (hi only). 1024 thr, 16 waves, 256^2.
// A LDS [256][32] (swizzle s^((r>>1)&3)), ring-3 (48KB), staged 2 tiles ahead;
// B direct global->VGPR 1 tile ahead. vmcnt(5) pre-MFMA; barrier only.
// ============================================================================
template<bool BIAS, bool STATS>
__global__ __launch_bounds__(1024)
void gemm1_v3(const f16* __restrict__ A_, const f16* __restrict__ B_,
              float* __restrict__ C, const float* __restrict__ bias,
              double* __restrict__ ssum, double* __restrict__ ssq,
              int M, int N, int K)
{
    __shared__ f16 sA[3][8192];
    const int tid = threadIdx.x, lane = tid & 63, w = tid >> 6;
    const int wr = w >> 2, wn = w & 3;
    const int gx = gridDim.x;
    int id = blockIdx.x + gx * blockIdx.y;
    const int nwg = gx * gridDim.y;
    id = (id & 7) * (nwg >> 3) + (id >> 3);
    const int row0 = (id % gx) * 256, col0 = (id / gx) * 256;
    const int KT = K >> 5;

    // A staging: 1 gload_lds/wave/tile covering 16 rows x 4 slots
    const int q = (lane & 3) ^ ((lane >> 3) & 3);
    const int r0 = w * 16 + (lane >> 2);
    const f16* srcA = A_ + (size_t)(row0 + r0) * K + q * 8;
    const int dstoff = w * 16 * 32;

    const int l15 = lane & 15, sl = lane >> 4;
    size_t offB[4];
#pragma unroll
    for (int n = 0; n < 4; ++n)
        offB[n] = (size_t)(col0 + wn * 64 + n * 16 + l15) * K + sl * 8;

    int rdA[4];
#pragma unroll
    for (int m = 0; m < 4; ++m) {
        const int rA = wr * 64 + m * 16 + l15;
        rdA[m] = rA * 32 + ((sl ^ ((rA >> 1) & 3)) << 3);
    }

    floatx4 acc[4][4];
#pragma unroll
    for (int m = 0; m < 4; ++m)
#pragma unroll
        for (int n = 0; n < 4; ++n)
#pragma unroll
            for (int j = 0; j < 4; ++j) acc[m][n][j] = 0.f;

    half8 bf0[4], bf1[4];

    // ---- prologue: A(0)->buf0, B(0)->set0, A(1)->buf1 ----
    GLLDS(srcA, &sA[0][dstoff]);
#pragma unroll
    for (int n = 0; n < 4; ++n) bf0[n] = *(const half8*)(B_ + offB[n]);
    {
        const int k1 = (KT > 1 ? 1 : 0) << 5;
        GLLDS(srcA + k1, &sA[1][dstoff]);
    }
    VMCNT(5);            // A(0) landed (B(0)x4 + A(1) in flight)
    __builtin_amdgcn_s_barrier();

#define G1_BODY(pcur, ptgt, bfc, bfn, kt_)                                        \
  {                                                                               \
    const int k2_ = ((kt_) + 2 < KT ? (kt_) + 2 : KT - 1) << 5;                   \
    const int k1_ = ((kt_) + 1 < KT ? (kt_) + 1 : KT - 1) << 5;                   \
    half8 afh[4];                                                                 \
    _Pragma("unroll") for (int m = 0; m < 4; ++m)                                 \
        afh[m] = *(const half8*)((pcur) + rdA[m]);                                \
    GLLDS(srcA + k2_, (ptgt) + dstoff);                                           \
    _Pragma("unroll") for (int n = 0; n < 4; ++n)                                 \
        bfn[n] = *(const half8*)(B_ + offB[n] + k1_);                             \
    VMCNT(5); LGKMCNT0;                                                           \
    __builtin_amdgcn_sched_barrier(0);                                            \
    __builtin_amdgcn_s_setprio(1);                                                \
    _Pragma("unroll") for (int m = 0; m < 4; ++m)                                 \
      _Pragma("unroll") for (int n = 0; n < 4; ++n)                               \
        acc[m][n] = __builtin_amdgcn_mfma_f32_16x16x32_f16(afh[m], bfc[n], acc[m][n], 0, 0, 0); \
    __builtin_amdgcn_s_setprio(0);                                                \
    __builtin_amdgcn_s_barrier();                                                 \
  }

    f16* c0 = &sA[0][0];
    f16* c1 = &sA[1][0];
    f16* c2 = &sA[2][0];
    for (int kt = 0; kt < KT; kt += 2) {
        G1_BODY(c0, c2, bf0, bf1, kt);
        { f16* t = c0; c0 = c1; c1 = c2; c2 = t; }
        G1_BODY(c0, c2, bf1, bf0, kt + 1);
        { f16* t = c0; c0 = c1; c1 = c2; c2 = t; }
    }
    VMCNT(0);
#undef G1_BODY

    const int cb0 = col0 + wn * 64;
    const int rb0 = row0 + wr * 64 + (lane >> 4) * 4;
#pragma unroll
    for (int n = 0; n < 4; ++n) {
        const int col = cb0 + n * 16 + l15;
        const float bv = BIAS ? bias[col] : 0.f;
        double sd = 0.0, sq = 0.0;
#pragma unroll
        for (int m = 0; m < 4; ++m) {
            const int row = rb0 + m * 16;
#pragma unroll
            for (int j = 0; j < 4; ++j) {
                const float v = acc[m][n][j] + bv;
                C[(size_t)(row + j) * N + col] = v;
                if (STATS) { sd += (double)v; sq += (double)v * (double)v; }
            }
        }
        if (STATS) {
            sd += __shfl_xor(sd, 16); sd += __shfl_xor(sd, 32);
            sq += __shfl_xor(sq, 16); sq += __shfl_xor(sq, 32);
            if (lane < 16) { atomicAdd(ssum + col, sd); atomicAdd(ssq + col, sq); }
        }
    }
}

// f32 -> (hi,lo) fp16 split, vectorized
__global__ void split_f32(const float* __restrict__ X, f16* __restrict__ hi,
                          f16* __restrict__ lo, size_t n4)
{
    const size_t stride = (size_t)gridDim.x * blockDim.x;
    for (size_t i = (size_t)blockIdx.x * blockDim.x + threadIdx.x; i < n4; i += stride) {
        const floatx4 x = ((const floatx4*)X)[i];
        half4 h, l;
#pragma unroll
        for (int j = 0; j < 4; ++j) {
            const float v = x[j];
            const f16 hv = (f16)v;
            h[j] = hv;
            l[j] = (f16)(v - (float)hv);
        }
        ((half4*)hi)[i] = h;
        ((half4*)lo)[i] = l;
    }
}

// BN affine + LeakyReLU, output f16 (optionally hi/lo split)
template<bool SPLIT>
__global__ void bn_apply(const float* __restrict__ X, const float* __restrict__ scale,
                         const float* __restrict__ shift, f16* __restrict__ Yhi,
                         f16* __restrict__ Ylo, size_t n4, int Nmask)
{
    const size_t stride = (size_t)gridDim.x * blockDim.x;
    for (size_t i = (size_t)blockIdx.x * blockDim.x + threadIdx.x; i < n4; i += stride) {
        const floatx4 x = ((const floatx4*)X)[i];
        const int col = (int)((i * 4) & (size_t)Nmask);
        half4 h, l;
#pragma unroll
        for (int j = 0; j < 4; ++j) {
            float v = x[j] * scale[col + j] + shift[col + j];
            v = v >= 0.f ? v : 0.01f * v;
            const f16 hv = (f16)v;
            h[j] = hv;
            if (SPLIT) l[j] = (f16)(v - (float)hv);
        }
        ((half4*)Yhi)[i] = h;
        if (SPLIT) ((half4*)Ylo)[i] = l;
    }
}

__global__ void bn_finalize(const double* __restrict__ ssum, const double* __restrict__ ssq,
                            const float* __restrict__ g, const float* __restrict__ b,
                            float* __restrict__ scale, float* __restrict__ shift, int N)
{
    const int j = blockIdx.x * blockDim.x + threadIdx.x;
    if (j < N) {
        const double inv = 1.0 / (double)NB;
        const double mean = ssum[j] * inv;
        const double var  = ssq[j] * inv - mean * mean;
        const double sc   = (double)g[j] / sqrt(var + 1e-5);
        scale[j] = (float)sc;
        shift[j] = (float)((double)b[j] - mean * sc);
    }
}

// W[K,N] f32 -> T[N,K] f16 (optionally with lo residual)
template<bool SPLIT>
__global__ void transpose_split(const float* __restrict__ W, f16* __restrict__ Thi,
                                f16* __restrict__ Tlo, int K, int N)
{
    __shared__ float tile[32][33];
    const int x = threadIdx.x;
    const int y = threadIdx.y;
    const int nt = blockIdx.x * 32;
    const int kt = blockIdx.y * 32;
#pragma unroll
    for (int i = 0; i < 32; i += 8)
        tile[y + i][x] = W[(size_t)(kt + y + i) * N + nt + x];
    __syncthreads();
#pragma unroll
    for (int i = 0; i < 32; i += 8) {
        const float v = tile[x][y + i];
        const size_t o = (size_t)(nt + y + i) * K + kt + x;
        const f16 hv = (f16)v;
        Thi[o] = hv;
        if (SPLIT) Tlo[o] = (f16)(v - (float)hv);
    }
}

__global__ void cnorm_kernel(const float* __restrict__ cb, float* __restrict__ cn)
{
    const int k = blockIdx.x * blockDim.x + threadIdx.x;
    if (k < (int)KCB) {
        double s = 0.0;
        for (int d = 0; d < (int)CD; ++d) {
            const float v = cb[(size_t)d * KCB + k];
            s += (double)v * v;
        }
        cn[k] = (float)s;
    }
}

// dist[b,k] = cnorm[k] - 2*S[b,k]; first-index argmin; gather z_q
__global__ void argmin_gather(const float* __restrict__ S, const float* __restrict__ cn,
                              const float* __restrict__ cb, float* __restrict__ zq,
                              float* __restrict__ idx_out, f16* __restrict__ zqh)
{
    const int lane = threadIdx.x & 63;
    const int row  = blockIdx.x * 4 + (threadIdx.x >> 6);
    const float* Sr = S + (size_t)row * KCB;
    float best = 3.4e38f;
    int bi = 0;
#pragma unroll
    for (int i = 0; i < 8; ++i) {
        const int k = lane + 64 * i;
        const float d = cn[k] - 2.f * Sr[k];
        if (d < best) { best = d; bi = k; }
    }
#pragma unroll
    for (int off = 32; off > 0; off >>= 1) {
        const float ob = __shfl_xor(best, off);
        const int   oi = __shfl_xor(bi, off);
        if (ob < best || (ob == best && oi < bi)) { best = ob; bi = oi; }
    }
    if (lane == 0) idx_out[row] = (float)bi;
#pragma unroll
    for (int i = 0; i < 4; ++i) {
        const int d = lane + 64 * i;
        const float v = cb[(size_t)d * KCB + bi];
        zq[(size_t)row * CD + d]  = v;
        zqh[(size_t)row * CD + d] = (f16)v;
    }
}

extern "C" void kernel_launch(void* const* d_in, const int* in_sizes, int n_in,
                              void* d_out, int out_size, void* d_ws, size_t ws_size,
                              hipStream_t stream)
{
    (void)in_sizes; (void)n_in; (void)out_size; (void)ws_size;
    const float* h   = (const float*)d_in[0];
    const float* ew1 = (const float*)d_in[1];
    const float* bg1 = (const float*)d_in[2];
    const float* bb1 = (const float*)d_in[3];
    const float* ew2 = (const float*)d_in[4];
    const float* bg2 = (const float*)d_in[5];
    const float* bb2 = (const float*)d_in[6];
    const float* ew3 = (const float*)d_in[7];
    const float* eb3 = (const float*)d_in[8];
    const float* cb  = (const float*)d_in[9];
    const float* dw1 = (const float*)d_in[10];
    const float* dg1 = (const float*)d_in[11];
    const float* db1 = (const float*)d_in[12];
    const float* dw2 = (const float*)d_in[13];
    const float* dg2 = (const float*)d_in[14];
    const float* db2 = (const float*)d_in[15];
    const float* dw3 = (const float*)d_in[16];
    const float* db3 = (const float*)d_in[17];

    char* ws = (char*)d_ws;
    float* out = (float*)d_out;

    f16* Hh  = (f16*)(ws + O_HH);
    f16* Hl  = (f16*)(ws + O_HL);
    f16* W1h = (f16*)(ws + O_W1H);
    f16* W1l = (f16*)(ws + O_W1L);
    f16* W2h = (f16*)(ws + O_W2H);
    f16* W2l = (f16*)(ws + O_W2L);
    f16* W3h = (f16*)(ws + O_W3H);
    f16* W3l = (f16*)(ws + O_W3L);
    f16* CBh = (f16*)(ws + O_CBH);
    f16* CBl = (f16*)(ws + O_CBL);
    f16* D1t = (f16*)(ws + O_DW1);
    f16* D2t = (f16*)(ws + O_DW2);
    f16* D3t = (f16*)(ws + O_DW3);
    double* sum0 = (double*)(ws + O_SUM);
    double* sq0  = (double*)(ws + O_SQ);
    float* sc0 = (float*)(ws + O_SC);
    float* sh0 = (float*)(ws + O_SH);
    float* cn  = (float*)(ws + O_CN);

    float* X1f = (float*)(ws + R2_X1F);
    f16*  X1h = (f16*)(ws + R_X1H);
    f16*  X1l = (f16*)(ws + R_X1L);
    float* X2f = (float*)(ws + R_X2F);
    f16*  X2h = (f16*)(ws + R_X2H);
    f16*  X2l = (f16*)(ws + R_X2L);
    f16*  Zeh = (f16*)(ws + R2_ZEH);
    f16*  Zel = (f16*)(ws + R2_ZEL);
    float* Sb  = (float*)(ws + R2_S);
    f16*  Zqh = (f16*)(ws + R2_ZQH);
    float* Y1f = (float*)(ws + R_Y1F);
    f16*  Y1h = (f16*)(ws + R_Y1H);
    float* Y2f = (float*)(ws + R2_Y2F);
    f16*  Y2h = (f16*)(ws + R_Y2H);

    hipMemsetAsync(ws + O_SUM, 0, 4 * 1024 * 8 * 2, stream);

    // input conversions
    split_f32<<<2048, 256, 0, stream>>>(h, Hh, Hl, NB * DH / 4);
    transpose_split<true ><<<dim3(F1 / 32, DH / 32), dim3(32, 8), 0, stream>>>(ew1, W1h, W1l, DH, F1);
    transpose_split<true ><<<dim3(F2 / 32, F1 / 32), dim3(32, 8), 0, stream>>>(ew2, W2h, W2l, F1, F2);
    transpose_split<true ><<<dim3(CD / 32, F2 / 32), dim3(32, 8), 0, stream>>>(ew3, W3h, W3l, F2, CD);
    transpose_split<true ><<<dim3(KCB / 32, CD / 32), dim3(32, 8), 0, stream>>>(cb, CBh, CBl, CD, KCB);
    transpose_split<false><<<dim3(F2 / 32, CD / 32), dim3(32, 8), 0, stream>>>(dw1, D1t, nullptr, CD, F2);
    transpose_split<false><<<dim3(F1 / 32, F2 / 32), dim3(32, 8), 0, stream>>>(dw2, D2t, nullptr, F2, F1);
    transpose_split<false><<<dim3(DH / 32, F1 / 32), dim3(32, 8), 0, stream>>>(dw3, D3t, nullptr, F1, DH);

    // ---- encoder ----
    gemm3_v3<false, true><<<dim3(NB / 256, F1 / 256), 1024, 0, stream>>>(
        Hh, Hl, W1h, W1l, X1f, nullptr, sum0, sq0, NB, F1, DH);
    bn_finalize<<<4, 256, 0, stream>>>(sum0, sq0, bg1, bb1, sc0, sh0, F1);
    bn_apply<true><<<2048, 256, 0, stream>>>(X1f, sc0, sh0, X1h, X1l, NB * F1 / 4, (int)F1 - 1);

    gemm3_v3<false, true><<<dim3(NB / 256, F2 / 256), 1024, 0, stream>>>(
        X1h, X1l, W2h, W2l, X2f, nullptr, sum0 + 1024, sq0 + 1024, NB, F2, F1);
    bn_finalize<<<2, 256, 0, stream>>>(sum0 + 1024, sq0 + 1024, bg2, bb2, sc0 + 1024, sh0 + 1024, F2);
    bn_apply<true><<<2048, 256, 0, stream>>>(X2f, sc0 + 1024, sh0 + 1024, X2h, X2l, NB * F2 / 4, (int)F2 - 1);

    gemm3_v3<true, false><<<dim3(NB / 256, CD / 256), 1024, 0, stream>>>(
        X2h, X2l, W3h, W3l, out + ZE_OFF, eb3, nullptr, nullptr, NB, CD, F2);

    // ---- quantize ----
    split_f32<<<2048, 256, 0, stream>>>(out + ZE_OFF, Zeh, Zel, NB * CD / 4);
    cnorm_kernel<<<2, 256, 0, stream>>>(cb, cn);
    gemm3_v3<false, false><<<dim3(NB / 256, KCB / 256), 1024, 0, stream>>>(
        Zeh, Zel, CBh, CBl, Sb, nullptr, nullptr, nullptr, NB, KCB, CD);
    argmin_gather<<<NB / 4, 256, 0, stream>>>(Sb, cn, cb, out + ZQ_OFF, out + IDX_OFF, Zqh);

    // ---- decoder ----
    gemm1_v3<false, true><<<dim3(NB / 256, F2 / 256), 1024, 0, stream>>>(
        Zqh, D1t, Y1f, nullptr, sum0 + 2048, sq0 + 2048, NB, F2, CD);
    bn_finalize<<<2, 256, 0, stream>>>(sum0 + 2048, sq0 + 2048, dg1, db1, sc0 + 2048, sh0 + 2048, F2);
    bn_apply<false><<<2048, 256, 0, stream>>>(Y1f, sc0 + 2048, sh0 + 2048, Y1h, nullptr, NB * F2 / 4, (int)F2 - 1);

    gemm1_v3<false, true><<<dim3(NB / 256, F1 / 256), 1024, 0, stream>>>(
        Y1h, D2t, Y2f, nullptr, sum0 + 3072, sq0 + 3072, NB, F1, F2);
    bn_finalize<<<4, 256, 0, stream>>>(sum0 + 3072, sq0 + 3072, dg2, db2, sc0 + 3072, sh0 + 3072, F1);
    bn_apply<false><<<2048, 256, 0, stream>>>(Y2f, sc0 + 3072, sh0 + 3072, Y2h, nullptr, NB * F1 / 4, (int)F1 - 1);

    gemm1_v3<true, false><<<dim3(NB / 256, DH / 256), 1024, 0, stream>>>(
        Y2h, D3t, out + HR_OFF, db3, nullptr, nullptr, NB, DH, F1);
}

// Round 6
// 613.713 us; speedup vs baseline: 5.0072x; 5.0072x over previous
//
#include <hip/hip_runtime.h>
#include <hip/hip_fp16.h>
#include <cstdint>
#include <cstddef>

typedef _Float16 f16;
typedef _Float16 half8 __attribute__((ext_vector_type(8)));
typedef _Float16 half4 __attribute__((ext_vector_type(4)));
typedef float floatx4 __attribute__((ext_vector_type(4)));

static constexpr size_t NB  = 16384;
static constexpr size_t DH  = 2048;
static constexpr size_t F1  = 1024;
static constexpr size_t F2  = 512;
static constexpr size_t CD  = 256;
static constexpr size_t KCB = 512;

// ---- d_out element offsets (all float32) ----
static constexpr size_t ZE_OFF  = 0;
static constexpr size_t ZQ_OFF  = NB * CD;
static constexpr size_t HR_OFF  = 2 * NB * CD;
static constexpr size_t IDX_OFF = 2 * NB * CD + NB * DH;

// ---- workspace byte offsets ----
static constexpr size_t O_HH   = 0;                   // h hi [NB,DH] f16
static constexpr size_t O_HL   = O_HH + NB * DH * 2;  // h lo
static constexpr size_t R1_END = O_HL + NB * DH * 2;

static constexpr size_t R_X1H = 0;                    // [NB,F1] f16
static constexpr size_t R_X1L = NB * F1 * 2;
static constexpr size_t R_X2F = 2 * NB * F1 * 2;      // [NB,F2] f32
static constexpr size_t R_X2H = R_X2F + NB * F2 * 4;
static constexpr size_t R_X2L = R_X2H + NB * F2 * 2;
static constexpr size_t R_Y1F = 0;                    // [NB,F2] f32
static constexpr size_t R_Y1H = NB * F2 * 4;          // [NB,F2] f16
static constexpr size_t R_Y2H = 0;                    // [NB,F1] f16

static constexpr size_t O_W1H = R1_END;
static constexpr size_t O_W1L = O_W1H + F1 * DH * 2;
static constexpr size_t O_W2H = O_W1L + F1 * DH * 2;
static constexpr size_t O_W2L = O_W2H + F2 * F1 * 2;
static constexpr size_t O_W3H = O_W2L + F2 * F1 * 2;
static constexpr size_t O_W3L = O_W3H + CD * F2 * 2;
static constexpr size_t O_CBH = O_W3L + CD * F2 * 2;
static constexpr size_t O_CBL = O_CBH + KCB * CD * 2;
static constexpr size_t O_DW1 = O_CBL + KCB * CD * 2;
static constexpr size_t O_DW2 = O_DW1 + F2 * CD * 2;
static constexpr size_t O_DW3 = O_DW2 + F1 * F2 * 2;
static constexpr size_t O_SUM = O_DW3 + DH * F1 * 2;  // 4 layers x 1024 doubles
static constexpr size_t O_SQ  = O_SUM + 4 * 1024 * 8;
static constexpr size_t O_SC  = O_SQ + 4 * 1024 * 8;
static constexpr size_t O_SH  = O_SC + 4 * 1024 * 4;
static constexpr size_t O_CN  = O_SH + 4 * 1024 * 4;
static constexpr size_t R2    = (O_CN + 4096 + 255) & ~(size_t)255;
static constexpr size_t R2_X1F = R2;                  // [NB,F1] f32
static constexpr size_t R2_ZEH = R2;                  // [NB,CD] f16
static constexpr size_t R2_ZEL = R2 + NB * CD * 2;
static constexpr size_t R2_S   = R2 + 2 * NB * CD * 2;   // [NB,KCB] f32
static constexpr size_t R2_ZQH = R2_S + NB * KCB * 4;    // [NB,CD] f16
static constexpr size_t R2_Y2F = R2;                  // [NB,F1] f32

#define GLLDS(src, dst)                                                          \
    __builtin_amdgcn_global_load_lds(                                            \
        (const __attribute__((address_space(1))) void*)(src),                    \
        (__attribute__((address_space(3))) void*)(dst), 16, 0, 0)

#define VMCNT(n)  asm volatile("s_waitcnt vmcnt(" #n ")" ::: "memory")
#define LGKMCNT0  asm volatile("s_waitcnt lgkmcnt(0)" ::: "memory")

// ============================================================================
// Fused 3-product GEMM (T2+T3+T4+T5), tile height templated.
// C[M,N] = Ah*Bh^T + Ah*Bl^T + Al*Bh^T, f32 accum. BM=MW*32, BN=256, BK=32.
// 8 waves (2M x 4N), wave tile (MW*16) x 64. LDS: 2 dbuf x 2 planes (H,L);
// plane = [256 rows][64 f16]: slots 0-3 = A rows (wrapped to BM), 4-7 = B,
// XOR bank swizzle slot ^= (row&7) applied on the pre-swizzled global source
// and on the ds_read address (same involution).
// Per K-tile: 3 phases {hh, hl, lh}; stage-issue 4/2/2; vmcnt(4) at ph1/ph3.
// WSPLIT: epilogue also writes f16 hi/lo of C (for the following dist GEMM).
// ============================================================================
template<int MW, bool BIAS, bool STATS, bool WSPLIT>
__global__ __launch_bounds__(512)
void gemm3_t(const f16* __restrict__ Ah_, const f16* __restrict__ Al_,
             const f16* __restrict__ Bh_, const f16* __restrict__ Bl_,
             float* __restrict__ C, const float* __restrict__ bias,
             double* __restrict__ ssum, double* __restrict__ ssq,
             f16* __restrict__ zeh, f16* __restrict__ zel,
             int M, int N, int K)
{
    constexpr int BM = MW * 32;
    __shared__ f16 lds[2][2][16384];   // [buf][plane H/L][256*64]
    const int tid  = threadIdx.x;
    const int lane = tid & 63;
    const int w    = tid >> 6;
    const int wr   = w >> 2, wn = w & 3;
    const int row0 = blockIdx.x * BM;
    const int col0 = blockIdx.y * 256;

    // ---- staging source addresses (pre-swizzled per lane) ----
    const int rr8 = lane >> 3;               // row within 8-row chunk
    const int p   = (lane & 7) ^ rr8;        // logical slot this lane must fetch
    const int rr  = w * 32 + rr8;            // plane row (j adds 8)
    const int arr = rr & (BM - 1);           // A row (wrap-dup when BM < 256)
    const f16* srcH = (p < 4) ? (Ah_ + (size_t)(row0 + arr) * K + p * 8)
                              : (Bh_ + (size_t)(col0 + rr) * K + (p - 4) * 8);
    const f16* srcL = (p < 4) ? (Al_ + (size_t)(row0 + arr) * K + p * 8)
                              : (Bl_ + (size_t)(col0 + rr) * K + (p - 4) * 8);
    const int dstBase = w * 32 * 64;         // f16 elems within plane
    const int KT = K >> 5;

    floatx4 acc[MW][4];
#pragma unroll
    for (int m = 0; m < MW; ++m)
#pragma unroll
        for (int n = 0; n < 4; ++n)
#pragma unroll
            for (int j = 0; j < 4; ++j) acc[m][n][j] = 0.f;

    const int l15 = lane & 15;
    const int sA  = lane >> 4;               // k-slot 0..3 (A); B uses 4+sA

    // ---- prologue: stage H(0), L(0) into buf 0 ----
#pragma unroll
    for (int j = 0; j < 4; ++j)
        GLLDS(srcH + (size_t)j * 8 * K, &lds[0][0][dstBase + j * 512]);
#pragma unroll
    for (int j = 0; j < 4; ++j)
        GLLDS(srcL + (size_t)j * 8 * K, &lds[0][1][dstBase + j * 512]);
    VMCNT(4);                                 // H(0) landed (L(0) in flight)
    __builtin_amdgcn_s_barrier();

    half8 afh[MW], afl[MW], bfh[4], bfl[4];

    for (int kt = 0; kt < KT; ++kt) {
        const int cur = kt & 1, nxt = cur ^ 1;
        const int koff = (kt + 1 < KT ? kt + 1 : kt) << 5;
        const f16* plH = lds[cur][0];
        const f16* plL = lds[cur][1];

        // ===== phase 1 : hh =====
#pragma unroll
        for (int m = 0; m < MW; ++m) {
            const int rA = wr * (MW * 16) + m * 16 + l15;
            afh[m] = *(const half8*)(plH + rA * 64 + (((sA) ^ (rA & 7)) << 3));
        }
#pragma unroll
        for (int n = 0; n < 4; ++n) {
            const int rB = wn * 64 + n * 16 + l15;
            bfh[n] = *(const half8*)(plH + rB * 64 + (((4 + sA) ^ (rB & 7)) << 3));
        }
#pragma unroll
        for (int j = 0; j < 4; ++j)
            GLLDS(srcH + (size_t)j * 8 * K + koff, &lds[nxt][0][dstBase + j * 512]);
        VMCNT(4);                             // L(kt) landed
        __builtin_amdgcn_s_barrier();
        LGKMCNT0;
        __builtin_amdgcn_sched_barrier(0);
        __builtin_amdgcn_s_setprio(1);
#pragma unroll
        for (int m = 0; m < MW; ++m)
#pragma unroll
            for (int n = 0; n < 4; ++n)
                acc[m][n] = __builtin_amdgcn_mfma_f32_16x16x32_f16(afh[m], bfh[n], acc[m][n], 0, 0, 0);
        __builtin_amdgcn_s_setprio(0);
        __builtin_amdgcn_s_barrier();

        // ===== phase 2 : hl (A-hi x B-lo) =====
#pragma unroll
        for (int n = 0; n < 4; ++n) {
            const int rB = wn * 64 + n * 16 + l15;
            bfl[n] = *(const half8*)(plL + rB * 64 + (((4 + sA) ^ (rB & 7)) << 3));
        }
#pragma unroll
        for (int j = 0; j < 2; ++j)
            GLLDS(srcL + (size_t)j * 8 * K + koff, &lds[nxt][1][dstBase + j * 512]);
        __builtin_amdgcn_s_barrier();
        LGKMCNT0;
        __builtin_amdgcn_sched_barrier(0);
        __builtin_amdgcn_s_setprio(1);
#pragma unroll
        for (int m = 0; m < MW; ++m)
#pragma unroll
            for (int n = 0; n < 4; ++n)
                acc[m][n] = __builtin_amdgcn_mfma_f32_16x16x32_f16(afh[m], bfl[n], acc[m][n], 0, 0, 0);
        __builtin_amdgcn_s_setprio(0);
        __builtin_amdgcn_s_barrier();

        // ===== phase 3 : lh (A-lo x B-hi) =====
#pragma unroll
        for (int m = 0; m < MW; ++m) {
            const int rA = wr * (MW * 16) + m * 16 + l15;
            afl[m] = *(const half8*)(plL + rA * 64 + (((sA) ^ (rA & 7)) << 3));
        }
#pragma unroll
        for (int j = 2; j < 4; ++j)
            GLLDS(srcL + (size_t)j * 8 * K + koff, &lds[nxt][1][dstBase + j * 512]);
        VMCNT(4);                             // H(kt+1) landed for next ph1
        __builtin_amdgcn_s_barrier();
        LGKMCNT0;
        __builtin_amdgcn_sched_barrier(0);
        __builtin_amdgcn_s_setprio(1);
#pragma unroll
        for (int m = 0; m < MW; ++m)
#pragma unroll
            for (int n = 0; n < 4; ++n)
                acc[m][n] = __builtin_amdgcn_mfma_f32_16x16x32_f16(afl[m], bfh[n], acc[m][n], 0, 0, 0);
        __builtin_amdgcn_s_setprio(0);
        __builtin_amdgcn_s_barrier();
    }
    VMCNT(0);

    // ---- epilogue: C/D layout col = lane&15, row = (lane>>4)*4 + j ----
    const int cb0 = col0 + wn * 64;
    const int rb0 = row0 + wr * (MW * 16) + (lane >> 4) * 4;
#pragma unroll
    for (int n = 0; n < 4; ++n) {
        const int col = cb0 + n * 16 + l15;
        const float bv = BIAS ? bias[col] : 0.f;
        double sd = 0.0, sq = 0.0;
#pragma unroll
        for (int m = 0; m < MW; ++m) {
            const int row = rb0 + m * 16;
#pragma unroll
            for (int j = 0; j < 4; ++j) {
                const float v = acc[m][n][j] + bv;
                const size_t o = (size_t)(row + j) * N + col;
                C[o] = v;
                if (WSPLIT) {
                    const f16 hv = (f16)v;
                    zeh[o] = hv;
                    zel[o] = (f16)(v - (float)hv);
                }
                if (STATS) { sd += (double)v; sq += (double)v * (double)v; }
            }
        }
        if (STATS) {
            sd += __shfl_xor(sd, 16);
            sd += __shfl_xor(sd, 32);
            sq += __shfl_xor(sq, 16);
            sq += __shfl_xor(sq, 32);
            if (lane < 16) {
                atomicAdd(ssum + col, sd);
                atomicAdd(ssq + col, sq);
            }
        }
    }
}

// ============================================================================
// Single-product variant (decoder). 3-buffer ring (stage 2 tiles ahead) so
// vmcnt stays counted (4). 2 phases per K-tile, 16 MFMA each.
// ============================================================================
template<bool BIAS, bool STATS>
__global__ __launch_bounds__(512)
void gemm1_8ph(const f16* __restrict__ A_, const f16* __restrict__ B_,
               float* __restrict__ C, const float* __restrict__ bias,
               double* __restrict__ ssum, double* __restrict__ ssq,
               int M, int N, int K)
{
    __shared__ f16 lds[3][16384];
    const int tid  = threadIdx.x;
    const int lane = tid & 63;
    const int w    = tid >> 6;
    const int wr   = w >> 2, wn = w & 3;
    const int row0 = blockIdx.x * 256;
    const int col0 = blockIdx.y * 256;

    const int rr8 = lane >> 3;
    const int p   = (lane & 7) ^ rr8;
    const int rr  = w * 32 + rr8;
    const f16* srcH = (p < 4) ? (A_ + (size_t)(row0 + rr) * K + p * 8)
                              : (B_ + (size_t)(col0 + rr) * K + (p - 4) * 8);
    const int dstBase = w * 32 * 64;
    const int KT = K >> 5;

    floatx4 acc[8][4];
#pragma unroll
    for (int m = 0; m < 8; ++m)
#pragma unroll
        for (int n = 0; n < 4; ++n)
#pragma unroll
            for (int j = 0; j < 4; ++j) acc[m][n][j] = 0.f;

    const int l15 = lane & 15;
    const int sA  = lane >> 4;

    // prologue: stage H(0)->buf0, H(1)->buf1
#pragma unroll
    for (int j = 0; j < 4; ++j)
        GLLDS(srcH + (size_t)j * 8 * K, &lds[0][dstBase + j * 512]);
    {
        const int k1 = (KT > 1 ? 1 : 0) << 5;
#pragma unroll
        for (int j = 0; j < 4; ++j)
            GLLDS(srcH + (size_t)j * 8 * K + k1, &lds[1][dstBase + j * 512]);
    }
    VMCNT(4);
    __builtin_amdgcn_s_barrier();

    half8 afh[8], bfh[4];

    for (int kt = 0; kt < KT; ++kt) {
        const int cur = kt % 3, tgt = (kt + 2) % 3;
        const int koff = (kt + 2 < KT ? kt + 2 : KT - 1) << 5;
        const f16* plH = lds[cur];

        // ===== phase 1 =====
#pragma unroll
        for (int m = 0; m < 8; ++m) {
            const int rA = wr * 128 + m * 16 + l15;
            afh[m] = *(const half8*)(plH + rA * 64 + (((sA) ^ (rA & 7)) << 3));
        }
#pragma unroll
        for (int n = 0; n < 4; ++n) {
            const int rB = wn * 64 + n * 16 + l15;
            bfh[n] = *(const half8*)(plH + rB * 64 + (((4 + sA) ^ (rB & 7)) << 3));
        }
#pragma unroll
        for (int j = 0; j < 2; ++j)
            GLLDS(srcH + (size_t)j * 8 * K + koff, &lds[tgt][dstBase + j * 512]);
        __builtin_amdgcn_s_barrier();
        LGKMCNT0;
        __builtin_amdgcn_sched_barrier(0);
        __builtin_amdgcn_s_setprio(1);
#pragma unroll
        for (int m = 0; m < 8; ++m)
#pragma unroll
            for (int n = 0; n < 2; ++n)
                acc[m][n] = __builtin_amdgcn_mfma_f32_16x16x32_f16(afh[m], bfh[n], acc[m][n], 0, 0, 0);
        __builtin_amdgcn_s_setprio(0);
        __builtin_amdgcn_s_barrier();

        // ===== phase 2 =====
#pragma unroll
        for (int j = 2; j < 4; ++j)
            GLLDS(srcH + (size_t)j * 8 * K + koff, &lds[tgt][dstBase + j * 512]);
        VMCNT(4);                             // H(kt+1) landed for next ph1
        __builtin_amdgcn_s_barrier();
        __builtin_amdgcn_s_setprio(1);
#pragma unroll
        for (int m = 0; m < 8; ++m)
#pragma unroll
            for (int n = 2; n < 4; ++n)
                acc[m][n] = __builtin_amdgcn_mfma_f32_16x16x32_f16(afh[m], bfh[n], acc[m][n], 0, 0, 0);
        __builtin_amdgcn_s_setprio(0);
        __builtin_amdgcn_s_barrier();
    }
    VMCNT(0);

    const int cb0 = col0 + wn * 64;
    const int rb0 = row0 + wr * 128 + (lane >> 4) * 4;
#pragma unroll
    for (int n = 0; n < 4; ++n) {
        const int col = cb0 + n * 16 + l15;
        const float bv = BIAS ? bias[col] : 0.f;
        double sd = 0.0, sq = 0.0;
#pragma unroll
        for (int m = 0; m < 8; ++m) {
            const int row = rb0 + m * 16;
#pragma unroll
            for (int j = 0; j < 4; ++j) {
                const float v = acc[m][n][j] + bv;
                C[(size_t)(row + j) * N + col] = v;
                if (STATS) { sd += (double)v; sq += (double)v * (double)v; }
            }
        }
        if (STATS) {
            sd += __shfl_xor(sd, 16);
            sd += __shfl_xor(sd, 32);
            sq += __shfl_xor(sq, 16);
            sq += __shfl_xor(sq, 32);
            if (lane < 16) {
                atomicAdd(ssum + col, sd);
                atomicAdd(ssq + col, sq);
            }
        }
    }
}

// f32 -> (hi,lo) fp16 split, vectorized
__global__ void split_f32(const float* __restrict__ X, f16* __restrict__ hi,
                          f16* __restrict__ lo, size_t n4)
{
    const size_t stride = (size_t)gridDim.x * blockDim.x;
    for (size_t i = (size_t)blockIdx.x * blockDim.x + threadIdx.x; i < n4; i += stride) {
        const floatx4 x = ((const floatx4*)X)[i];
        half4 h, l;
#pragma unroll
        for (int j = 0; j < 4; ++j) {
            const float v = x[j];
            const f16 hv = (f16)v;
            h[j] = hv;
            l[j] = (f16)(v - (float)hv);
        }
        ((half4*)hi)[i] = h;
        ((half4*)lo)[i] = l;
    }
}

// BN affine + LeakyReLU, output f16 (optionally hi/lo split)
template<bool SPLIT>
__global__ void bn_apply(const float* __restrict__ X, const float* __restrict__ scale,
                         const float* __restrict__ shift, f16* __restrict__ Yhi,
                         f16* __restrict__ Ylo, size_t n4, int Nmask)
{
    const size_t stride = (size_t)gridDim.x * blockDim.x;
    for (size_t i = (size_t)blockIdx.x * blockDim.x + threadIdx.x; i < n4; i += stride) {
        const floatx4 x = ((const floatx4*)X)[i];
        const int col = (int)((i * 4) & (size_t)Nmask);
        half4 h, l;
#pragma unroll
        for (int j = 0; j < 4; ++j) {
            float v = x[j] * scale[col + j] + shift[col + j];
            v = v >= 0.f ? v : 0.01f * v;
            const f16 hv = (f16)v;
            h[j] = hv;
            if (SPLIT) l[j] = (f16)(v - (float)hv);
        }
        ((half4*)Yhi)[i] = h;
        if (SPLIT) ((half4*)Ylo)[i] = l;
    }
}

__global__ void bn_finalize(const double* __restrict__ ssum, const double* __restrict__ ssq,
                            const float* __restrict__ g, const float* __restrict__ b,
                            float* __restrict__ scale, float* __restrict__ shift, int N)
{
    const int j = blockIdx.x * blockDim.x + threadIdx.x;
    if (j < N) {
        const double inv = 1.0 / (double)NB;
        const double mean = ssum[j] * inv;
        const double var  = ssq[j] * inv - mean * mean;
        const double sc   = (double)g[j] / sqrt(var + 1e-5);
        scale[j] = (float)sc;
        shift[j] = (float)((double)b[j] - mean * sc);
    }
}

// W[K,N] f32 -> T[N,K] f16 (optionally with lo residual)
template<bool SPLIT>
__global__ void transpose_split(const float* __restrict__ W, f16* __restrict__ Thi,
                                f16* __restrict__ Tlo, int K, int N)
{
    __shared__ float tile[32][33];
    const int x = threadIdx.x;
    const int y = threadIdx.y;
    const int nt = blockIdx.x * 32;
    const int kt = blockIdx.y * 32;
#pragma unroll
    for (int i = 0; i < 32; i += 8)
        tile[y + i][x] = W[(size_t)(kt + y + i) * N + nt + x];
    __syncthreads();
#pragma unroll
    for (int i = 0; i < 32; i += 8) {
        const float v = tile[x][y + i];
        const size_t o = (size_t)(nt + y + i) * K + kt + x;
        const f16 hv = (f16)v;
        Thi[o] = hv;
        if (SPLIT) Tlo[o] = (f16)(v - (float)hv);
    }
}

__global__ void cnorm_kernel(const float* __restrict__ cb, float* __restrict__ cn)
{
    const int k = blockIdx.x * blockDim.x + threadIdx.x;
    if (k < (int)KCB) {
        double s = 0.0;
        for (int d = 0; d < (int)CD; ++d) {
            const float v = cb[(size_t)d * KCB + k];
            s += (double)v * v;
        }
        cn[k] = (float)s;
    }
}

// dist[b,k] = cnorm[k] - 2*S[b,k]; first-index argmin; gather z_q
__global__ void argmin_gather(const float* __restrict__ S, const float* __restrict__ cn,
                              const float* __restrict__ cb, float* __restrict__ zq,
                              float* __restrict__ idx_out, f16* __restrict__ zqh)
{
    const int lane = threadIdx.x & 63;
    const int row  = blockIdx.x * 4 + (threadIdx.x >> 6);
    const float* Sr = S + (size_t)row * KCB;
    float best = 3.4e38f;
    int bi = 0;
#pragma unroll
    for (int i = 0; i < 8; ++i) {
        const int k = lane + 64 * i;
        const float d = cn[k] - 2.f * Sr[k];
        if (d < best) { best = d; bi = k; }
    }
#pragma unroll
    for (int off = 32; off > 0; off >>= 1) {
        const float ob = __shfl_xor(best, off);
        const int   oi = __shfl_xor(bi, off);
        if (ob < best || (ob == best && oi < bi)) { best = ob; bi = oi; }
    }
    if (lane == 0) idx_out[row] = (float)bi;
#pragma unroll
    for (int i = 0; i < 4; ++i) {
        const int d = lane + 64 * i;
        const float v = cb[(size_t)d * KCB + bi];
        zq[(size_t)row * CD + d]  = v;
        zqh[(size_t)row * CD + d] = (f16)v;
    }
}

extern "C" void kernel_launch(void* const* d_in, const int* in_sizes, int n_in,
                              void* d_out, int out_size, void* d_ws, size_t ws_size,
                              hipStream_t stream)
{
    (void)in_sizes; (void)n_in; (void)out_size; (void)ws_size;
    const float* h   = (const float*)d_in[0];
    const float* ew1 = (const float*)d_in[1];
    const float* bg1 = (const float*)d_in[2];
    const float* bb1 = (const float*)d_in[3];
    const float* ew2 = (const float*)d_in[4];
    const float* bg2 = (const float*)d_in[5];
    const float* bb2 = (const float*)d_in[6];
    const float* ew3 = (const float*)d_in[7];
    const float* eb3 = (const float*)d_in[8];
    const float* cb  = (const float*)d_in[9];
    const float* dw1 = (const float*)d_in[10];
    const float* dg1 = (const float*)d_in[11];
    const float* db1 = (const float*)d_in[12];
    const float* dw2 = (const float*)d_in[13];
    const float* dg2 = (const float*)d_in[14];
    const float* db2 = (const float*)d_in[15];
    const float* dw3 = (const float*)d_in[16];
    const float* db3 = (const float*)d_in[17];

    char* ws = (char*)d_ws;
    float* out = (float*)d_out;

    f16* Hh  = (f16*)(ws + O_HH);
    f16* Hl  = (f16*)(ws + O_HL);
    f16* W1h = (f16*)(ws + O_W1H);
    f16* W1l = (f16*)(ws + O_W1L);
    f16* W2h = (f16*)(ws + O_W2H);
    f16* W2l = (f16*)(ws + O_W2L);
    f16* W3h = (f16*)(ws + O_W3H);
    f16* W3l = (f16*)(ws + O_W3L);
    f16* CBh = (f16*)(ws + O_CBH);
    f16* CBl = (f16*)(ws + O_CBL);
    f16* D1t = (f16*)(ws + O_DW1);
    f16* D2t = (f16*)(ws + O_DW2);
    f16* D3t = (f16*)(ws + O_DW3);
    double* sum0 = (double*)(ws + O_SUM);
    double* sq0  = (double*)(ws + O_SQ);
    float* sc0 = (float*)(ws + O_SC);
    float* sh0 = (float*)(ws + O_SH);
    float* cn  = (float*)(ws + O_CN);

    float* X1f = (float*)(ws + R2_X1F);
    f16*  X1h = (f16*)(ws + R_X1H);
    f16*  X1l = (f16*)(ws + R_X1L);
    float* X2f = (float*)(ws + R_X2F);
    f16*  X2h = (f16*)(ws + R_X2H);
    f16*  X2l = (f16*)(ws + R_X2L);
    f16*  Zeh = (f16*)(ws + R2_ZEH);
    f16*  Zel = (f16*)(ws + R2_ZEL);
    float* Sb  = (float*)(ws + R2_S);
    f16*  Zqh = (f16*)(ws + R2_ZQH);
    float* Y1f = (float*)(ws + R_Y1F);
    f16*  Y1h = (f16*)(ws + R_Y1H);
    float* Y2f = (float*)(ws + R2_Y2F);
    f16*  Y2h = (f16*)(ws + R_Y2H);

    hipMemsetAsync(ws + O_SUM, 0, 4 * 1024 * 8 * 2, stream);

    // input conversions
    split_f32<<<2048, 256, 0, stream>>>(h, Hh, Hl, NB * DH / 4);
    transpose_split<true ><<<dim3(F1 / 32, DH / 32), dim3(32, 8), 0, stream>>>(ew1, W1h, W1l, DH, F1);
    transpose_split<true ><<<dim3(F2 / 32, F1 / 32), dim3(32, 8), 0, stream>>>(ew2, W2h, W2l, F1, F2);
    transpose_split<true ><<<dim3(CD / 32, F2 / 32), dim3(32, 8), 0, stream>>>(ew3, W3h, W3l, F2, CD);
    transpose_split<true ><<<dim3(KCB / 32, CD / 32), dim3(32, 8), 0, stream>>>(cb, CBh, CBl, CD, KCB);
    transpose_split<false><<<dim3(F2 / 32, CD / 32), dim3(32, 8), 0, stream>>>(dw1, D1t, nullptr, CD, F2);
    transpose_split<false><<<dim3(F1 / 32, F2 / 32), dim3(32, 8), 0, stream>>>(dw2, D2t, nullptr, F2, F1);
    transpose_split<false><<<dim3(DH / 32, F1 / 32), dim3(32, 8), 0, stream>>>(dw3, D3t, nullptr, F1, DH);

    // ---- encoder ----
    gemm3_t<8, false, true, false><<<dim3(NB / 256, F1 / 256), 512, 0, stream>>>(
        Hh, Hl, W1h, W1l, X1f, nullptr, sum0, sq0, nullptr, nullptr, NB, F1, DH);
    bn_finalize<<<4, 256, 0, stream>>>(sum0, sq0, bg1, bb1, sc0, sh0, F1);
    bn_apply<true><<<2048, 256, 0, stream>>>(X1f, sc0, sh0, X1h, X1l, NB * F1 / 4, (int)F1 - 1);

    gemm3_t<4, false, true, false><<<dim3(NB / 128, F2 / 256), 512, 0, stream>>>(
        X1h, X1l, W2h, W2l, X2f, nullptr, sum0 + 1024, sq0 + 1024, nullptr, nullptr, NB, F2, F1);
    bn_finalize<<<2, 256, 0, stream>>>(sum0 + 1024, sq0 + 1024, bg2, bb2, sc0 + 1024, sh0 + 1024, F2);
    bn_apply<true><<<2048, 256, 0, stream>>>(X2f, sc0 + 1024, sh0 + 1024, X2h, X2l, NB * F2 / 4, (int)F2 - 1);

    gemm3_t<4, true, false, true><<<dim3(NB / 128, CD / 256), 512, 0, stream>>>(
        X2h, X2l, W3h, W3l, out + ZE_OFF, eb3, nullptr, nullptr, Zeh, Zel, NB, CD, F2);

    // ---- quantize ----
    cnorm_kernel<<<2, 256, 0, stream>>>(cb, cn);
    gemm3_t<4, false, false, false><<<dim3(NB / 128, KCB / 256), 512, 0, stream>>>(
        Zeh, Zel, CBh, CBl, Sb, nullptr, nullptr, nullptr, nullptr, nullptr, NB, KCB, CD);
    argmin_gather<<<NB / 4, 256, 0, stream>>>(Sb, cn, cb, out + ZQ_OFF, out + IDX_OFF, Zqh);

    // ---- decoder ----
    gemm1_8ph<false, true><<<dim3(NB / 256, F2 / 256), 512, 0, stream>>>(
        Zqh, D1t, Y1f, nullptr, sum0 + 2048, sq0 + 2048, NB, F2, CD);
    bn_finalize<<<2, 256, 0, stream>>>(sum0 + 2048, sq0 + 2048, dg1, db1, sc0 + 2048, sh0 + 2048, F2);
    bn_apply<false><<<2048, 256, 0, stream>>>(Y1f, sc0 + 2048, sh0 + 2048, Y1h, nullptr, NB * F2 / 4, (int)F2 - 1);

    gemm1_8ph<false, true><<<dim3(NB / 256, F1 / 256), 512, 0, stream>>>(
        Y1h, D2t, Y2f, nullptr, sum0 + 3072, sq0 + 3072, NB, F1, F2);
    bn_finalize<<<4, 256, 0, stream>>>(sum0 + 3072, sq0 + 3072, dg2, db2, sc0 + 3072, sh0 + 3072, F1);
    bn_apply<false><<<2048, 256, 0, stream>>>(Y2f, sc0 + 3072, sh0 + 3072, Y2h, nullptr, NB * F1 / 4, (int)F1 - 1);

    gemm1_8ph<true, false><<<dim3(NB / 256, DH / 256), 512, 0, stream>>>(
        Y2h, D3t, out + HR_OFF, db3, nullptr, nullptr, NB, DH, F1);
}

// Round 7
// 598.373 us; speedup vs baseline: 5.1356x; 1.0256x over previous
//
#include <hip/hip_runtime.h>
#include <hip/hip_fp16.h>
#include <cstdint>
#include <cstddef>

typedef _Float16 f16;
typedef _Float16 half8 __attribute__((ext_vector_type(8)));
typedef _Float16 half4 __attribute__((ext_vector_type(4)));
typedef float floatx4 __attribute__((ext_vector_type(4)));

static constexpr size_t NB  = 16384;
static constexpr size_t DH  = 2048;
static constexpr size_t F1  = 1024;
static constexpr size_t F2  = 512;
static constexpr size_t CD  = 256;
static constexpr size_t KCB = 512;

// ---- d_out element offsets (all float32) ----
static constexpr size_t ZE_OFF  = 0;
static constexpr size_t ZQ_OFF  = NB * CD;
static constexpr size_t HR_OFF  = 2 * NB * CD;
static constexpr size_t IDX_OFF = 2 * NB * CD + NB * DH;

// ---- workspace byte offsets ----
static constexpr size_t O_HH   = 0;                   // h hi [NB,DH] f16
static constexpr size_t O_HL   = O_HH + NB * DH * 2;  // h lo
static constexpr size_t R1_END = O_HL + NB * DH * 2;

static constexpr size_t R_X1H = 0;                    // [NB,F1] f16
static constexpr size_t R_X1L = NB * F1 * 2;
static constexpr size_t R_X2F = 2 * NB * F1 * 2;      // [NB,F2] f32
static constexpr size_t R_X2H = R_X2F + NB * F2 * 4;
static constexpr size_t R_X2L = R_X2H + NB * F2 * 2;
static constexpr size_t R_Y1F = 0;                    // [NB,F2] f32
static constexpr size_t R_Y1H = NB * F2 * 4;          // [NB,F2] f16
static constexpr size_t R_Y2H = 0;                    // [NB,F1] f16

static constexpr size_t O_W1H = R1_END;
static constexpr size_t O_W1L = O_W1H + F1 * DH * 2;
static constexpr size_t O_W2H = O_W1L + F1 * DH * 2;
static constexpr size_t O_W2L = O_W2H + F2 * F1 * 2;
static constexpr size_t O_W3H = O_W2L + F2 * F1 * 2;
static constexpr size_t O_W3L = O_W3H + CD * F2 * 2;
static constexpr size_t O_CBH = O_W3L + CD * F2 * 2;
static constexpr size_t O_CBL = O_CBH + KCB * CD * 2;
static constexpr size_t O_DW1 = O_CBL + KCB * CD * 2;
static constexpr size_t O_DW2 = O_DW1 + F2 * CD * 2;
static constexpr size_t O_DW3 = O_DW2 + F1 * F2 * 2;
static constexpr size_t O_SUM = O_DW3 + DH * F1 * 2;  // 4 layers x 1024 doubles
static constexpr size_t O_SQ  = O_SUM + 4 * 1024 * 8;
static constexpr size_t O_SC  = O_SQ + 4 * 1024 * 8;
static constexpr size_t O_SH  = O_SC + 4 * 1024 * 4;
static constexpr size_t O_CN  = O_SH + 4 * 1024 * 4;
static constexpr size_t R2    = (O_CN + 4096 + 255) & ~(size_t)255;
static constexpr size_t R2_X1F = R2;                  // [NB,F1] f32
static constexpr size_t R2_ZEH = R2;                  // [NB,CD] f16
static constexpr size_t R2_ZEL = R2 + NB * CD * 2;
static constexpr size_t R2_S   = R2 + 2 * NB * CD * 2;   // [NB,KCB] f32
static constexpr size_t R2_ZQH = R2_S + NB * KCB * 4;    // [NB,CD] f16
static constexpr size_t R2_Y2F = R2;                  // [NB,F1] f32

#define GLLDS(src, dst)                                                          \
    __builtin_amdgcn_global_load_lds(                                            \
        (const __attribute__((address_space(1))) void*)(src),                    \
        (__attribute__((address_space(3))) void*)(dst), 16, 0, 0)

#define VMCNT(n)  asm volatile("s_waitcnt vmcnt(" #n ")" ::: "memory")
#define LGKMCNT0  asm volatile("s_waitcnt lgkmcnt(0)" ::: "memory")

// bijective XCD chunk swizzle (requires nwg % 8 == 0; all our grids comply)
__device__ __forceinline__ void xcd_tile(int gx, int BM, int& row0, int& col0)
{
    int id = blockIdx.x + gx * blockIdx.y;
    const int nwg = gx * gridDim.y;
    id = (id & 7) * (nwg >> 3) + (id >> 3);
    row0 = (id % gx) * BM;
    col0 = (id / gx) * 256;
}

// ============================================================================
// Fused 3-product GEMM: C = Ah*Bh^T + Ah*Bl^T + Al*Bh^T, f32 accum.
// BM=MW*32, BN=256, BK=32. 8 waves (2M x 4N). LDS: 2 dbuf x 2 planes (H,L);
// plane [256 rows][64 f16]: slots 0-3 = A rows (wrapped to BM), 4-7 = B;
// XOR swizzle slot ^= (row&7) on pre-swizzled global source and ds_read.
// MERGED 2-phase schedule, 2 barriers/K-tile, counted vmcnt(4) (never 0):
//  ph1: read H-frags | stage H(t+1) | 32 MFMA hh | vmcnt(4)=drain L(t) | bar
//  ph2: read L-frags | stage L(t+1) | 64 MFMA hl,lh | vmcnt(4)=drain H(t+1) | bar
// ============================================================================
template<int MW, bool BIAS, bool STATS, bool WSPLIT>
__global__ __launch_bounds__(512)
void gemm3_t(const f16* __restrict__ Ah_, const f16* __restrict__ Al_,
             const f16* __restrict__ Bh_, const f16* __restrict__ Bl_,
             float* __restrict__ C, const float* __restrict__ bias,
             double* __restrict__ ssum, double* __restrict__ ssq,
             f16* __restrict__ zeh, f16* __restrict__ zel,
             int M, int N, int K)
{
    constexpr int BM = MW * 32;
    __shared__ f16 lds[2][2][16384];   // [buf][plane H/L][256*64]
    const int tid  = threadIdx.x;
    const int lane = tid & 63;
    const int w    = tid >> 6;
    const int wr   = w >> 2, wn = w & 3;
    int row0, col0;
    xcd_tile(gridDim.x, BM, row0, col0);

    // ---- staging source addresses (pre-swizzled per lane) ----
    const int rr8 = lane >> 3;               // row within 8-row chunk
    const int p   = (lane & 7) ^ rr8;        // logical slot this lane must fetch
    const int rr  = w * 32 + rr8;            // plane row (j adds 8)
    const int arr = rr & (BM - 1);           // A row (wrap-dup when BM < 256)
    const f16* srcH = (p < 4) ? (Ah_ + (size_t)(row0 + arr) * K + p * 8)
                              : (Bh_ + (size_t)(col0 + rr) * K + (p - 4) * 8);
    const f16* srcL = (p < 4) ? (Al_ + (size_t)(row0 + arr) * K + p * 8)
                              : (Bl_ + (size_t)(col0 + rr) * K + (p - 4) * 8);
    const int dstBase = w * 32 * 64;         // f16 elems within plane
    const int KT = K >> 5;

    floatx4 acc[MW][4];
#pragma unroll
    for (int m = 0; m < MW; ++m)
#pragma unroll
        for (int n = 0; n < 4; ++n)
#pragma unroll
            for (int j = 0; j < 4; ++j) acc[m][n][j] = 0.f;

    const int l15 = lane & 15;
    const int sA  = lane >> 4;               // k-slot 0..3 (A); B uses 4+sA

    // ---- prologue: stage H(0), L(0) into buf 0 ----
#pragma unroll
    for (int j = 0; j < 4; ++j)
        GLLDS(srcH + (size_t)j * 8 * K, &lds[0][0][dstBase + j * 512]);
#pragma unroll
    for (int j = 0; j < 4; ++j)
        GLLDS(srcL + (size_t)j * 8 * K, &lds[0][1][dstBase + j * 512]);
    VMCNT(4);                                 // H(0) landed (L(0) in flight)
    __builtin_amdgcn_s_barrier();

    half8 afh[MW], afl[MW], bfh[4], bfl[4];

    for (int kt = 0; kt < KT; ++kt) {
        const int cur = kt & 1, nxt = cur ^ 1;
        const int koff = (kt + 1 < KT ? kt + 1 : kt) << 5;
        const f16* plH = lds[cur][0];
        const f16* plL = lds[cur][1];

        // ===== phase 1 : hh =====
#pragma unroll
        for (int m = 0; m < MW; ++m) {
            const int rA = wr * (MW * 16) + m * 16 + l15;
            afh[m] = *(const half8*)(plH + rA * 64 + (((sA) ^ (rA & 7)) << 3));
        }
#pragma unroll
        for (int n = 0; n < 4; ++n) {
            const int rB = wn * 64 + n * 16 + l15;
            bfh[n] = *(const half8*)(plH + rB * 64 + (((4 + sA) ^ (rB & 7)) << 3));
        }
#pragma unroll
        for (int j = 0; j < 4; ++j)
            GLLDS(srcH + (size_t)j * 8 * K + koff, &lds[nxt][0][dstBase + j * 512]);
        LGKMCNT0;
        __builtin_amdgcn_sched_barrier(0);
        __builtin_amdgcn_s_setprio(1);
#pragma unroll
        for (int m = 0; m < MW; ++m)
#pragma unroll
            for (int n = 0; n < 4; ++n)
                acc[m][n] = __builtin_amdgcn_mfma_f32_16x16x32_f16(afh[m], bfh[n], acc[m][n], 0, 0, 0);
        __builtin_amdgcn_s_setprio(0);
        VMCNT(4);                             // L(kt) landed (H(kt+1) in flight)
        __builtin_amdgcn_s_barrier();

        // ===== phase 2 : hl + lh =====
#pragma unroll
        for (int n = 0; n < 4; ++n) {
            const int rB = wn * 64 + n * 16 + l15;
            bfl[n] = *(const half8*)(plL + rB * 64 + (((4 + sA) ^ (rB & 7)) << 3));
        }
#pragma unroll
        for (int m = 0; m < MW; ++m) {
            const int rA = wr * (MW * 16) + m * 16 + l15;
            afl[m] = *(const half8*)(plL + rA * 64 + (((sA) ^ (rA & 7)) << 3));
        }
#pragma unroll
        for (int j = 0; j < 4; ++j)
            GLLDS(srcL + (size_t)j * 8 * K + koff, &lds[nxt][1][dstBase + j * 512]);
        LGKMCNT0;
        __builtin_amdgcn_sched_barrier(0);
        __builtin_amdgcn_s_setprio(1);
#pragma unroll
        for (int m = 0; m < MW; ++m)
#pragma unroll
            for (int n = 0; n < 4; ++n)
                acc[m][n] = __builtin_amdgcn_mfma_f32_16x16x32_f16(afh[m], bfl[n], acc[m][n], 0, 0, 0);
#pragma unroll
        for (int m = 0; m < MW; ++m)
#pragma unroll
            for (int n = 0; n < 4; ++n)
                acc[m][n] = __builtin_amdgcn_mfma_f32_16x16x32_f16(afl[m], bfh[n], acc[m][n], 0, 0, 0);
        __builtin_amdgcn_s_setprio(0);
        VMCNT(4);                             // H(kt+1) landed (L(kt+1) in flight)
        __builtin_amdgcn_s_barrier();
    }
    VMCNT(0);

    // ---- epilogue: C/D layout col = lane&15, row = (lane>>4)*4 + j ----
    const int cb0 = col0 + wn * 64;
    const int rb0 = row0 + wr * (MW * 16) + (lane >> 4) * 4;
#pragma unroll
    for (int n = 0; n < 4; ++n) {
        const int col = cb0 + n * 16 + l15;
        const float bv = BIAS ? bias[col] : 0.f;
        double sd = 0.0, sq = 0.0;
#pragma unroll
        for (int m = 0; m < MW; ++m) {
            const int row = rb0 + m * 16;
#pragma unroll
            for (int j = 0; j < 4; ++j) {
                const float v = acc[m][n][j] + bv;
                const size_t o = (size_t)(row + j) * N + col;
                C[o] = v;
                if (WSPLIT) {
                    const f16 hv = (f16)v;
                    zeh[o] = hv;
                    zel[o] = (f16)(v - (float)hv);
                }
                if (STATS) { sd += (double)v; sq += (double)v * (double)v; }
            }
        }
        if (STATS) {
            sd += __shfl_xor(sd, 16);
            sd += __shfl_xor(sd, 32);
            sq += __shfl_xor(sq, 16);
            sq += __shfl_xor(sq, 32);
            if (lane < 16) {
                atomicAdd(ssum + col, sd);
                atomicAdd(ssq + col, sq);
            }
        }
    }
}

// ============================================================================
// Single-product GEMM (decoder): merged single phase per K-tile, ring-3
// buffers (stage 2 ahead), 1 barrier + vmcnt(4) per K-tile (never 0).
// plane [256 rows][64 f16]: slots 0-3 A (wrapped to BM), 4-7 B.
// ============================================================================
template<int MW, bool BIAS, bool STATS>
__global__ __launch_bounds__(512)
void gemm1_t(const f16* __restrict__ A_, const f16* __restrict__ B_,
             float* __restrict__ C, const float* __restrict__ bias,
             double* __restrict__ ssum, double* __restrict__ ssq,
             int M, int N, int K)
{
    constexpr int BM = MW * 32;
    __shared__ f16 lds[3][16384];
    const int tid  = threadIdx.x;
    const int lane = tid & 63;
    const int w    = tid >> 6;
    const int wr   = w >> 2, wn = w & 3;
    int row0, col0;
    xcd_tile(gridDim.x, BM, row0, col0);

    const int rr8 = lane >> 3;
    const int p   = (lane & 7) ^ rr8;
    const int rr  = w * 32 + rr8;
    const int arr = rr & (BM - 1);
    const f16* srcH = (p < 4) ? (A_ + (size_t)(row0 + arr) * K + p * 8)
                              : (B_ + (size_t)(col0 + rr) * K + (p - 4) * 8);
    const int dstBase = w * 32 * 64;
    const int KT = K >> 5;

    floatx4 acc[MW][4];
#pragma unroll
    for (int m = 0; m < MW; ++m)
#pragma unroll
        for (int n = 0; n < 4; ++n)
#pragma unroll
            for (int j = 0; j < 4; ++j) acc[m][n][j] = 0.f;

    const int l15 = lane & 15;
    const int sA  = lane >> 4;

    // prologue: stage (0)->buf0, (1)->buf1
#pragma unroll
    for (int j = 0; j < 4; ++j)
        GLLDS(srcH + (size_t)j * 8 * K, &lds[0][dstBase + j * 512]);
    {
        const int k1 = (KT > 1 ? 1 : 0) << 5;
#pragma unroll
        for (int j = 0; j < 4; ++j)
            GLLDS(srcH + (size_t)j * 8 * K + k1, &lds[1][dstBase + j * 512]);
    }
    VMCNT(4);                                 // buf0 landed (buf1 in flight)
    __builtin_amdgcn_s_barrier();

    half8 afh[MW], bfh[4];

    for (int kt = 0; kt < KT; ++kt) {
        const int cur = kt % 3, tgt = (kt + 2) % 3;
        const int koff = (kt + 2 < KT ? kt + 2 : KT - 1) << 5;
        const f16* plH = lds[cur];

#pragma unroll
        for (int m = 0; m < MW; ++m) {
            const int rA = wr * (MW * 16) + m * 16 + l15;
            afh[m] = *(const half8*)(plH + rA * 64 + (((sA) ^ (rA & 7)) << 3));
        }
#pragma unroll
        for (int n = 0; n < 4; ++n) {
            const int rB = wn * 64 + n * 16 + l15;
            bfh[n] = *(const half8*)(plH + rB * 64 + (((4 + sA) ^ (rB & 7)) << 3));
        }
#pragma unroll
        for (int j = 0; j < 4; ++j)
            GLLDS(srcH + (size_t)j * 8 * K + koff, &lds[tgt][dstBase + j * 512]);
        LGKMCNT0;
        __builtin_amdgcn_sched_barrier(0);
        __builtin_amdgcn_s_setprio(1);
#pragma unroll
        for (int m = 0; m < MW; ++m)
#pragma unroll
            for (int n = 0; n < 4; ++n)
                acc[m][n] = __builtin_amdgcn_mfma_f32_16x16x32_f16(afh[m], bfh[n], acc[m][n], 0, 0, 0);
        __builtin_amdgcn_s_setprio(0);
        VMCNT(4);                             // buf(kt+1) landed (buf(kt+2) in flight)
        __builtin_amdgcn_s_barrier();
    }
    VMCNT(0);

    const int cb0 = col0 + wn * 64;
    const int rb0 = row0 + wr * (MW * 16) + (lane >> 4) * 4;
#pragma unroll
    for (int n = 0; n < 4; ++n) {
        const int col = cb0 + n * 16 + l15;
        const float bv = BIAS ? bias[col] : 0.f;
        double sd = 0.0, sq = 0.0;
#pragma unroll
        for (int m = 0; m < MW; ++m) {
            const int row = rb0 + m * 16;
#pragma unroll
            for (int j = 0; j < 4; ++j) {
                const float v = acc[m][n][j] + bv;
                C[(size_t)(row + j) * N + col] = v;
                if (STATS) { sd += (double)v; sq += (double)v * (double)v; }
            }
        }
        if (STATS) {
            sd += __shfl_xor(sd, 16);
            sd += __shfl_xor(sd, 32);
            sq += __shfl_xor(sq, 16);
            sq += __shfl_xor(sq, 32);
            if (lane < 16) {
                atomicAdd(ssum + col, sd);
                atomicAdd(ssq + col, sq);
            }
        }
    }
}

// f32 -> (hi,lo) fp16 split, vectorized
__global__ void split_f32(const float* __restrict__ X, f16* __restrict__ hi,
                          f16* __restrict__ lo, size_t n4)
{
    const size_t stride = (size_t)gridDim.x * blockDim.x;
    for (size_t i = (size_t)blockIdx.x * blockDim.x + threadIdx.x; i < n4; i += stride) {
        const floatx4 x = ((const floatx4*)X)[i];
        half4 h, l;
#pragma unroll
        for (int j = 0; j < 4; ++j) {
            const float v = x[j];
            const f16 hv = (f16)v;
            h[j] = hv;
            l[j] = (f16)(v - (float)hv);
        }
        ((half4*)hi)[i] = h;
        ((half4*)lo)[i] = l;
    }
}

// BN affine + LeakyReLU, output f16 (optionally hi/lo split)
template<bool SPLIT>
__global__ void bn_apply(const float* __restrict__ X, const float* __restrict__ scale,
                         const float* __restrict__ shift, f16* __restrict__ Yhi,
                         f16* __restrict__ Ylo, size_t n4, int Nmask)
{
    const size_t stride = (size_t)gridDim.x * blockDim.x;
    for (size_t i = (size_t)blockIdx.x * blockDim.x + threadIdx.x; i < n4; i += stride) {
        const floatx4 x = ((const floatx4*)X)[i];
        const int col = (int)((i * 4) & (size_t)Nmask);
        half4 h, l;
#pragma unroll
        for (int j = 0; j < 4; ++j) {
            float v = x[j] * scale[col + j] + shift[col + j];
            v = v >= 0.f ? v : 0.01f * v;
            const f16 hv = (f16)v;
            h[j] = hv;
            if (SPLIT) l[j] = (f16)(v - (float)hv);
        }
        ((half4*)Yhi)[i] = h;
        if (SPLIT) ((half4*)Ylo)[i] = l;
    }
}

__global__ void bn_finalize(const double* __restrict__ ssum, const double* __restrict__ ssq,
                            const float* __restrict__ g, const float* __restrict__ b,
                            float* __restrict__ scale, float* __restrict__ shift, int N)
{
    const int j = blockIdx.x * blockDim.x + threadIdx.x;
    if (j < N) {
        const double inv = 1.0 / (double)NB;
        const double mean = ssum[j] * inv;
        const double var  = ssq[j] * inv - mean * mean;
        const double sc   = (double)g[j] / sqrt(var + 1e-5);
        scale[j] = (float)sc;
        shift[j] = (float)((double)b[j] - mean * sc);
    }
}

// W[K,N] f32 -> T[N,K] f16 (optionally with lo residual)
template<bool SPLIT>
__global__ void transpose_split(const float* __restrict__ W, f16* __restrict__ Thi,
                                f16* __restrict__ Tlo, int K, int N)
{
    __shared__ float tile[32][33];
    const int x = threadIdx.x;
    const int y = threadIdx.y;
    const int nt = blockIdx.x * 32;
    const int kt = blockIdx.y * 32;
#pragma unroll
    for (int i = 0; i < 32; i += 8)
        tile[y + i][x] = W[(size_t)(kt + y + i) * N + nt + x];
    __syncthreads();
#pragma unroll
    for (int i = 0; i < 32; i += 8) {
        const float v = tile[x][y + i];
        const size_t o = (size_t)(nt + y + i) * K + kt + x;
        const f16 hv = (f16)v;
        Thi[o] = hv;
        if (SPLIT) Tlo[o] = (f16)(v - (float)hv);
    }
}

__global__ void cnorm_kernel(const float* __restrict__ cb, float* __restrict__ cn)
{
    const int k = blockIdx.x * blockDim.x + threadIdx.x;
    if (k < (int)KCB) {
        double s = 0.0;
        for (int d = 0; d < (int)CD; ++d) {
            const float v = cb[(size_t)d * KCB + k];
            s += (double)v * v;
        }
        cn[k] = (float)s;
    }
}

// dist[b,k] = cnorm[k] - 2*S[b,k]; first-index argmin; gather z_q
__global__ void argmin_gather(const float* __restrict__ S, const float* __restrict__ cn,
                              const float* __restrict__ cb, float* __restrict__ zq,
                              float* __restrict__ idx_out, f16* __restrict__ zqh)
{
    const int lane = threadIdx.x & 63;
    const int row  = blockIdx.x * 4 + (threadIdx.x >> 6);
    const float* Sr = S + (size_t)row * KCB;
    float best = 3.4e38f;
    int bi = 0;
#pragma unroll
    for (int i = 0; i < 8; ++i) {
        const int k = lane + 64 * i;
        const float d = cn[k] - 2.f * Sr[k];
        if (d < best) { best = d; bi = k; }
    }
#pragma unroll
    for (int off = 32; off > 0; off >>= 1) {
        const float ob = __shfl_xor(best, off);
        const int   oi = __shfl_xor(bi, off);
        if (ob < best || (ob == best && oi < bi)) { best = ob; bi = oi; }
    }
    if (lane == 0) idx_out[row] = (float)bi;
#pragma unroll
    for (int i = 0; i < 4; ++i) {
        const int d = lane + 64 * i;
        const float v = cb[(size_t)d * KCB + bi];
        zq[(size_t)row * CD + d]  = v;
        zqh[(size_t)row * CD + d] = (f16)v;
    }
}

extern "C" void kernel_launch(void* const* d_in, const int* in_sizes, int n_in,
                              void* d_out, int out_size, void* d_ws, size_t ws_size,
                              hipStream_t stream)
{
    (void)in_sizes; (void)n_in; (void)out_size; (void)ws_size;
    const float* h   = (const float*)d_in[0];
    const float* ew1 = (const float*)d_in[1];
    const float* bg1 = (const float*)d_in[2];
    const float* bb1 = (const float*)d_in[3];
    const float* ew2 = (const float*)d_in[4];
    const float* bg2 = (const float*)d_in[5];
    const float* bb2 = (const float*)d_in[6];
    const float* ew3 = (const float*)d_in[7];
    const float* eb3 = (const float*)d_in[8];
    const float* cb  = (const float*)d_in[9];
    const float* dw1 = (const float*)d_in[10];
    const float* dg1 = (const float*)d_in[11];
    const float* db1 = (const float*)d_in[12];
    const float* dw2 = (const float*)d_in[13];
    const float* dg2 = (const float*)d_in[14];
    const float* db2 = (const float*)d_in[15];
    const float* dw3 = (const float*)d_in[16];
    const float* db3 = (const float*)d_in[17];

    char* ws = (char*)d_ws;
    float* out = (float*)d_out;

    f16* Hh  = (f16*)(ws + O_HH);
    f16* Hl  = (f16*)(ws + O_HL);
    f16* W1h = (f16*)(ws + O_W1H);
    f16* W1l = (f16*)(ws + O_W1L);
    f16* W2h = (f16*)(ws + O_W2H);
    f16* W2l = (f16*)(ws + O_W2L);
    f16* W3h = (f16*)(ws + O_W3H);
    f16* W3l = (f16*)(ws + O_W3L);
    f16* CBh = (f16*)(ws + O_CBH);
    f16* CBl = (f16*)(ws + O_CBL);
    f16* D1t = (f16*)(ws + O_DW1);
    f16* D2t = (f16*)(ws + O_DW2);
    f16* D3t = (f16*)(ws + O_DW3);
    double* sum0 = (double*)(ws + O_SUM);
    double* sq0  = (double*)(ws + O_SQ);
    float* sc0 = (float*)(ws + O_SC);
    float* sh0 = (float*)(ws + O_SH);
    float* cn  = (float*)(ws + O_CN);

    float* X1f = (float*)(ws + R2_X1F);
    f16*  X1h = (f16*)(ws + R_X1H);
    f16*  X1l = (f16*)(ws + R_X1L);
    float* X2f = (float*)(ws + R_X2F);
    f16*  X2h = (f16*)(ws + R_X2H);
    f16*  X2l = (f16*)(ws + R_X2L);
    f16*  Zeh = (f16*)(ws + R2_ZEH);
    f16*  Zel = (f16*)(ws + R2_ZEL);
    float* Sb  = (float*)(ws + R2_S);
    f16*  Zqh = (f16*)(ws + R2_ZQH);
    float* Y1f = (float*)(ws + R_Y1F);
    f16*  Y1h = (f16*)(ws + R_Y1H);
    float* Y2f = (float*)(ws + R2_Y2F);
    f16*  Y2h = (f16*)(ws + R_Y2H);

    hipMemsetAsync(ws + O_SUM, 0, 4 * 1024 * 8 * 2, stream);

    // input conversions
    split_f32<<<2048, 256, 0, stream>>>(h, Hh, Hl, NB * DH / 4);
    transpose_split<true ><<<dim3(F1 / 32, DH / 32), dim3(32, 8), 0, stream>>>(ew1, W1h, W1l, DH, F1);
    transpose_split<true ><<<dim3(F2 / 32, F1 / 32), dim3(32, 8), 0, stream>>>(ew2, W2h, W2l, F1, F2);
    transpose_split<true ><<<dim3(CD / 32, F2 / 32), dim3(32, 8), 0, stream>>>(ew3, W3h, W3l, F2, CD);
    transpose_split<true ><<<dim3(KCB / 32, CD / 32), dim3(32, 8), 0, stream>>>(cb, CBh, CBl, CD, KCB);
    transpose_split<false><<<dim3(F2 / 32, CD / 32), dim3(32, 8), 0, stream>>>(dw1, D1t, nullptr, CD, F2);
    transpose_split<false><<<dim3(F1 / 32, F2 / 32), dim3(32, 8), 0, stream>>>(dw2, D2t, nullptr, F2, F1);
    transpose_split<false><<<dim3(DH / 32, F1 / 32), dim3(32, 8), 0, stream>>>(dw3, D3t, nullptr, F1, DH);

    // ---- encoder ----
    gemm3_t<8, false, true, false><<<dim3(NB / 256, F1 / 256), 512, 0, stream>>>(
        Hh, Hl, W1h, W1l, X1f, nullptr, sum0, sq0, nullptr, nullptr, NB, F1, DH);
    bn_finalize<<<4, 256, 0, stream>>>(sum0, sq0, bg1, bb1, sc0, sh0, F1);
    bn_apply<true><<<2048, 256, 0, stream>>>(X1f, sc0, sh0, X1h, X1l, NB * F1 / 4, (int)F1 - 1);

    gemm3_t<4, false, true, false><<<dim3(NB / 128, F2 / 256), 512, 0, stream>>>(
        X1h, X1l, W2h, W2l, X2f, nullptr, sum0 + 1024, sq0 + 1024, nullptr, nullptr, NB, F2, F1);
    bn_finalize<<<2, 256, 0, stream>>>(sum0 + 1024, sq0 + 1024, bg2, bb2, sc0 + 1024, sh0 + 1024, F2);
    bn_apply<true><<<2048, 256, 0, stream>>>(X2f, sc0 + 1024, sh0 + 1024, X2h, X2l, NB * F2 / 4, (int)F2 - 1);

    gemm3_t<4, true, false, true><<<dim3(NB / 128, CD / 256), 512, 0, stream>>>(
        X2h, X2l, W3h, W3l, out + ZE_OFF, eb3, nullptr, nullptr, Zeh, Zel, NB, CD, F2);

    // ---- quantize ----
    cnorm_kernel<<<2, 256, 0, stream>>>(cb, cn);
    gemm3_t<4, false, false, false><<<dim3(NB / 128, KCB / 256), 512, 0, stream>>>(
        Zeh, Zel, CBh, CBl, Sb, nullptr, nullptr, nullptr, nullptr, nullptr, NB, KCB, CD);
    argmin_gather<<<NB / 4, 256, 0, stream>>>(Sb, cn, cb, out + ZQ_OFF, out + IDX_OFF, Zqh);

    // ---- decoder ----
    gemm1_t<4, false, true><<<dim3(NB / 128, F2 / 256), 512, 0, stream>>>(
        Zqh, D1t, Y1f, nullptr, sum0 + 2048, sq0 + 2048, NB, F2, CD);
    bn_finalize<<<2, 256, 0, stream>>>(sum0 + 2048, sq0 + 2048, dg1, db1, sc0 + 2048, sh0 + 2048, F2);
    bn_apply<false><<<2048, 256, 0, stream>>>(Y1f, sc0 + 2048, sh0 + 2048, Y1h, nullptr, NB * F2 / 4, (int)F2 - 1);

    gemm1_t<8, false, true><<<dim3(NB / 256, F1 / 256), 512, 0, stream>>>(
        Y1h, D2t, Y2f, nullptr, sum0 + 3072, sq0 + 3072, NB, F1, F2);
    bn_finalize<<<4, 256, 0, stream>>>(sum0 + 3072, sq0 + 3072, dg2, db2, sc0 + 3072, sh0 + 3072, F1);
    bn_apply<false><<<2048, 256, 0, stream>>>(Y2f, sc0 + 3072, sh0 + 3072, Y2h, nullptr, NB * F1 / 4, (int)F1 - 1);

    gemm1_t<8, true, false><<<dim3(NB / 256, DH / 256), 512, 0, stream>>>(
        Y2h, D3t, out + HR_OFF, db3, nullptr, nullptr, NB, DH, F1);
}